// Round 1
// baseline (47.441 us; speedup 1.0000x reference)
//
#include <hip/hip_runtime.h>

#define SMAPE_EPS 0.001f

// ---------------------------------------------------------------------------
// Kernel 1: grid-stride float4 streaming pass.
// Each thread accumulates its SMAPE-ratio partial sum in f32, then a
// wave-64 shuffle reduction + LDS cross-wave reduction produces one
// partial per block, written to d_ws (no atomics -> deterministic).
// ---------------------------------------------------------------------------
__global__ __launch_bounds__(256) void smape_partial_kernel(
    const float* __restrict__ pred,
    const float* __restrict__ targ,
    float* __restrict__ partial,
    long long n4,          // number of float4 elements
    long long n)           // total scalar elements (for tail)
{
    const float4* __restrict__ p4 = reinterpret_cast<const float4*>(pred);
    const float4* __restrict__ t4 = reinterpret_cast<const float4*>(targ);

    long long idx    = (long long)blockIdx.x * blockDim.x + threadIdx.x;
    long long stride = (long long)gridDim.x * blockDim.x;

    float acc = 0.0f;

    for (long long i = idx; i < n4; i += stride) {
        float4 a = p4[i];
        float4 b = t4[i];

        {
            float d = fabsf(a.x) + fabsf(b.x);
            float num = fabsf(b.x - a.x);
            acc += (d >= SMAPE_EPS) ? (num / d) : 0.0f;
        }
        {
            float d = fabsf(a.y) + fabsf(b.y);
            float num = fabsf(b.y - a.y);
            acc += (d >= SMAPE_EPS) ? (num / d) : 0.0f;
        }
        {
            float d = fabsf(a.z) + fabsf(b.z);
            float num = fabsf(b.z - a.z);
            acc += (d >= SMAPE_EPS) ? (num / d) : 0.0f;
        }
        {
            float d = fabsf(a.w) + fabsf(b.w);
            float num = fabsf(b.w - a.w);
            acc += (d >= SMAPE_EPS) ? (num / d) : 0.0f;
        }
    }

    // Scalar tail (n not divisible by 4) — handled by thread 0 of block 0.
    if (blockIdx.x == 0 && threadIdx.x == 0) {
        for (long long i = n4 * 4; i < n; ++i) {
            float a = pred[i];
            float b = targ[i];
            float d = fabsf(a) + fabsf(b);
            float num = fabsf(b - a);
            acc += (d >= SMAPE_EPS) ? (num / d) : 0.0f;
        }
    }

    // Wave-64 reduction.
    #pragma unroll
    for (int off = 32; off > 0; off >>= 1)
        acc += __shfl_down(acc, off, 64);

    // Cross-wave reduction via LDS (256 threads = 4 waves).
    __shared__ float warp_sums[4];
    int lane = threadIdx.x & 63;
    int wid  = threadIdx.x >> 6;
    if (lane == 0) warp_sums[wid] = acc;
    __syncthreads();

    if (threadIdx.x == 0) {
        float s = warp_sums[0] + warp_sums[1] + warp_sums[2] + warp_sums[3];
        partial[blockIdx.x] = s;
    }
}

// ---------------------------------------------------------------------------
// Kernel 2: single-block final reduction of per-block partials.
// ---------------------------------------------------------------------------
__global__ __launch_bounds__(256) void smape_final_kernel(
    const float* __restrict__ partial,
    int nblocks,
    float* __restrict__ out,
    float scale)
{
    float acc = 0.0f;
    for (int i = threadIdx.x; i < nblocks; i += blockDim.x)
        acc += partial[i];

    #pragma unroll
    for (int off = 32; off > 0; off >>= 1)
        acc += __shfl_down(acc, off, 64);

    __shared__ float warp_sums[4];
    int lane = threadIdx.x & 63;
    int wid  = threadIdx.x >> 6;
    if (lane == 0) warp_sums[wid] = acc;
    __syncthreads();

    if (threadIdx.x == 0) {
        float s = warp_sums[0] + warp_sums[1] + warp_sums[2] + warp_sums[3];
        out[0] = s * scale;
    }
}

extern "C" void kernel_launch(void* const* d_in, const int* in_sizes, int n_in,
                              void* d_out, int out_size, void* d_ws, size_t ws_size,
                              hipStream_t stream) {
    const float* pred = (const float*)d_in[0];
    const float* targ = (const float*)d_in[1];
    float* out        = (float*)d_out;
    float* partial    = (float*)d_ws;   // needs NBLOCKS * 4 bytes

    long long n  = (long long)in_sizes[0];
    long long n4 = n / 4;

    const int threads = 256;
    const int nblocks = 2048;  // 256 CUs x 8 blocks; grid-stride covers the rest

    // result = sum(ratio) * 200 / (S*B) = total * 200 / N
    float scale = (float)(200.0 / (double)n);

    smape_partial_kernel<<<nblocks, threads, 0, stream>>>(pred, targ, partial, n4, n);
    smape_final_kernel<<<1, threads, 0, stream>>>(partial, nblocks, out, scale);
}